// Round 8
// baseline (926.181 us; speedup 1.0000x reference)
//
#include <hip/hip_runtime.h>

#define N_NODES 50000
#define N_PAD   50048   // 391*128, GEMM drops all row guards
#define N_EDGES 800000
#define N_GRAPHS 512
#define F_IN 256
#define F_H 128
#define F_CAT 256

// bucketed CSR build
#define BSHIFT 9
#define NB 98           // ceil(50000/512) buckets
#define CAP 10240       // edge capacity per bucket (mean 8163, 23 sigma slack)
#define EPB 3125        // edges per scatter block (256 blocks)

// sliced aggregation work queues
#define CHUNK 256       // nodes per block-chunk (64 per wave)
#define NCHUNK 196      // ceil(50000/256)

typedef __attribute__((ext_vector_type(8))) short short8;
typedef __attribute__((ext_vector_type(4))) float f32x4;
typedef unsigned int uint;
typedef unsigned short ushort;

static __device__ __forceinline__ ushort f2bf(float f) {
    uint u = __float_as_uint(f);
    u += 0x7FFF + ((u >> 16) & 1);  // RNE
    return (ushort)(u >> 16);
}
static __device__ __forceinline__ float bflo(uint v) { return __uint_as_float(v << 16); }
static __device__ __forceinline__ float bfhi(uint v) { return __uint_as_float(v & 0xFFFF0000u); }
static __device__ __forceinline__ float bfu(ushort v) { return __uint_as_float((uint)v << 16); }

// physical XCD id (gfx940+: HW_REG_XCC_ID = hwreg 20) [learn_hip m09]
static __device__ __forceinline__ int get_xcc() {
    int x;
    asm("s_getreg_b32 %0, hwreg(20, 0, 32)" : "=s"(x));
    return x & 7;
}

// async global->LDS, 16B per lane; lds base must be wave-uniform
#define GLL(g, l) __builtin_amdgcn_global_load_lds( \
    (const __attribute__((address_space(1))) unsigned int*)(g), \
    (__attribute__((address_space(3))) unsigned int*)(l), 16, 0, 0)

// ---------------------------------------------------------------------------
// S1: bucket-scatter edges. gcur is RELATIVE (zero-initialized by memset).
__global__ __launch_bounds__(256) void csr_scatter_kernel(
        const int* __restrict__ ei, int* __restrict__ gcur,
        uint* __restrict__ ebuf_td, uint* __restrict__ ebuf_bu) {
    __shared__ int lcnt[256];   // [dir*128 + bucket]
    __shared__ int lbase[256];
    int tid = threadIdx.x;
    lcnt[tid] = 0;
    __syncthreads();
    int e0 = blockIdx.x * EPB;
    for (int k = tid; k < EPB; k += 256) {
        int i = e0 + k;
        int s = ei[i], d = ei[N_EDGES + i];
        atomicAdd(&lcnt[d >> BSHIFT], 1);
        atomicAdd(&lcnt[128 + (s >> BSHIFT)], 1);
    }
    __syncthreads();
    if (tid < 2 * NB) {
        int dir = tid / NB, b = tid % NB;
        int c = lcnt[dir * 128 + b];
        lbase[dir * 128 + b] = c ? atomicAdd(&gcur[dir * NB + b], c) : 0;
    }
    __syncthreads();
    lcnt[tid] = 0;
    __syncthreads();
    for (int k = tid; k < EPB; k += 256) {
        int i = e0 + k;
        int s = ei[i], d = ei[N_EDGES + i];
        int bd = d >> BSHIFT, bs = s >> BSHIFT;
        int p = atomicAdd(&lcnt[bd], 1) + lbase[bd];
        ebuf_td[(size_t)bd * CAP + p] = (uint)s | ((uint)(d & 511) << 16);
        int q = atomicAdd(&lcnt[128 + bs], 1) + lbase[128 + bs];
        ebuf_bu[(size_t)bs * CAP + q] = (uint)d | ((uint)(s & 511) << 16);
    }
}

// ---------------------------------------------------------------------------
// S2: per-(bucket,dir) CSR build, bucket-local scatter window
__global__ __launch_bounds__(256) void csr_build_kernel(
        const uint* __restrict__ ebuf_td, const uint* __restrict__ ebuf_bu,
        const int* __restrict__ gcur,
        int* off_td, int* off_bu, ushort* deg_td, ushort* deg_bu,
        float* dinv_td, float* dinv_bu, ushort* csr_td, ushort* csr_bu) {
    int b = blockIdx.x, dir = blockIdx.y;
    const uint* ebuf = dir ? ebuf_bu : ebuf_td;
    int* off     = dir ? off_bu : off_td;
    ushort* deg  = dir ? deg_bu : deg_td;
    float* dinv  = dir ? dinv_bu : dinv_td;
    ushort* csr  = dir ? csr_bu : csr_td;
    __shared__ int cntL[512], offL[512], sm[256];
    int tid = threadIdx.x;
    cntL[tid] = 0; cntL[tid + 256] = 0;
    __syncthreads();
    int rbeg = b * CAP;
    int rend = rbeg + gcur[dir * NB + b];
    for (int k = rbeg + tid; k < rend; k += 256)
        atomicAdd(&cntL[ebuf[k] >> 16], 1);
    __syncthreads();
    int a0 = cntL[tid * 2], a1 = cntL[tid * 2 + 1];
    int ps = a0 + a1;
    sm[tid] = ps;
    __syncthreads();
    for (int o = 1; o < 256; o <<= 1) {
        int u = (tid >= o) ? sm[tid - o] : 0;
        __syncthreads();
        sm[tid] += u;
        __syncthreads();
    }
    int excl = sm[tid] - ps;
    offL[tid * 2] = excl;
    offL[tid * 2 + 1] = excl + a0;
    __syncthreads();
    int nbase = b << BSHIFT;
#pragma unroll
    for (int j = 0; j < 2; j++) {
        int nloc = tid + j * 256;
        int n = nbase + nloc;
        if (n < N_NODES) {
            off[n] = rbeg + offL[nloc];
            int c = cntL[nloc];
            deg[n] = (ushort)c;
            dinv[n] = rsqrtf((float)c + 1.0f);
        }
    }
    cntL[tid] = offL[tid];
    cntL[tid + 256] = offL[tid + 256];
    __syncthreads();
    for (int k = rbeg + tid; k < rend; k += 256) {
        uint e = ebuf[k];
        int slot = atomicAdd(&cntL[e >> 16], 1);
        csr[rbeg + slot] = (ushort)(e & 0xFFFF);
    }
}

// ---------------------------------------------------------------------------
__global__ void cvt_x_kernel(const float* __restrict__ x, ushort* __restrict__ xb) {
    size_t i = (size_t)blockIdx.x * blockDim.x + threadIdx.x;  // float4 index
    ushort4 u = {0, 0, 0, 0};
    if (i < (size_t)N_NODES * (F_IN / 4)) {
        float4 f = ((const float4*)x)[i];
        u.x = f2bf(f.x); u.y = f2bf(f.y); u.z = f2bf(f.z); u.w = f2bf(f.w);
    }
    ((ushort4*)xb)[i] = u;
}

// ---------------------------------------------------------------------------
// Bt1[n][k]; Wt2[k][c] with c in concat([bu, td]) order.
__global__ void prep_w_kernel(const float* __restrict__ td_W1, const float* __restrict__ bu_W1,
                              const float* __restrict__ td_W2, const float* __restrict__ bu_W2,
                              ushort* __restrict__ Bt1, ushort* __restrict__ Wt2) {
    int n = blockIdx.x;   // 0..255
    int k = threadIdx.x;  // 0..255
    float w1 = (n < F_H) ? td_W1[(size_t)k * F_H + n] : bu_W1[(size_t)k * F_H + (n - F_H)];
    Bt1[(size_t)n * 256 + k] = f2bf(w1);
    if (k < 128) {
        float w2 = (n < F_H) ? bu_W2[(size_t)k * F_H + n]
                             : td_W2[(size_t)k * F_H + (n - F_H)];
        Wt2[(size_t)k * 256 + n] = f2bf(w2);
    }
}

// ---------------------------------------------------------------------------
// MFMA GEMM (layer 1): C = A[M,256] @ Bt1^T, row-scaled by branch dinv.
__global__ __launch_bounds__(256) void gemm_mfma(
        const ushort* __restrict__ A, const ushort* __restrict__ Bt,
        ushort* __restrict__ C,
        const float* __restrict__ dinv_td, const float* __restrict__ dinv_bu) {
    __shared__ __align__(16) ushort As[128 * 32];
    __shared__ __align__(16) ushort Bs[128 * 32];
    int tid = threadIdx.x;
    int wave = tid >> 6, lane = tid & 63, quad = lane >> 4, l16 = lane & 15;
    size_t bm = (size_t)blockIdx.x * 128;
    size_t bn = (size_t)blockIdx.y * 128;
    const float* dsel = blockIdx.y ? dinv_bu : dinv_td;

    f32x4 acc[2][8];
    const f32x4 z4 = {0.f, 0.f, 0.f, 0.f};
#pragma unroll
    for (int i = 0; i < 2; i++)
#pragma unroll
        for (int j = 0; j < 8; j++) acc[i][j] = z4;

    int cb0 = wave * 64;
    int cb1 = 256 + wave * 64;
    int c0 = cb0 + lane, c1 = cb1 + lane;
    int r0 = c0 >> 2, s0 = (c0 & 3) * 8;
    int r1 = c1 >> 2, s1 = (c1 & 3) * 8;
    const ushort* a0p = A + (bm + r0) * 256 + s0;
    const ushort* a1p = A + (bm + r1) * 256 + s1;
    const ushort* b0p = Bt + (bn + r0) * 256 + s0;
    const ushort* b1p = Bt + (bn + r1) * 256 + s1;
    ushort* lA0 = As + cb0 * 8;
    ushort* lA1 = As + cb1 * 8;
    ushort* lB0 = Bs + cb0 * 8;
    ushort* lB1 = Bs + cb1 * 8;

    for (int kb = 0; kb < 8; kb++) {
        int k0 = kb * 32;
        __syncthreads();
        GLL(a0p + k0, lA0);
        GLL(a1p + k0, lA1);
        GLL(b0p + k0, lB0);
        GLL(b1p + k0, lB1);
        __syncthreads();
        short8 af0 = *(const short8*)(As + (wave * 32 + l16) * 32 + quad * 8);
        short8 af1 = *(const short8*)(As + (wave * 32 + 16 + l16) * 32 + quad * 8);
#pragma unroll
        for (int ct = 0; ct < 8; ct++) {
            short8 bfr = *(const short8*)(Bs + (ct * 16 + l16) * 32 + quad * 8);
            acc[0][ct] = __builtin_amdgcn_mfma_f32_16x16x32_bf16(af0, bfr, acc[0][ct], 0, 0, 0);
            acc[1][ct] = __builtin_amdgcn_mfma_f32_16x16x32_bf16(af1, bfr, acc[1][ct], 0, 0, 0);
        }
    }
#pragma unroll
    for (int rt = 0; rt < 2; rt++) {
#pragma unroll
        for (int r = 0; r < 4; r++) {
            size_t row = bm + wave * 32 + rt * 16 + quad * 4 + r;
            float dv = dsel[row];
#pragma unroll
            for (int ct = 0; ct < 8; ct++) {
                C[row * 256 + bn + ct * 16 + l16] = f2bf(acc[rt][ct][r] * dv);
            }
        }
    }
}

// ---------------------------------------------------------------------------
// Sliced gather over a 32-col (64 B) slice. lane = e*16 + c: e = edge slot,
// c = col pair. base is pre-offset by colbase + c*2. Unroll-4 -> 16 lines
// in flight per wave. Result (full cross-e sum) left in a0,a1 after caller's
// shfl reduction.
static __device__ __forceinline__ void gather32(
        const ushort* __restrict__ base, const ushort* __restrict__ csr,
        int kb, int ke, int e, float& a0, float& a1) {
    float p0 = 0, p1 = 0, q0 = 0, q1 = 0, r0 = 0, r1 = 0;
    int k = kb;
    for (; k + 16 <= ke; k += 16) {
        int i0 = csr[k + e], i1 = csr[k + 4 + e];
        int i2 = csr[k + 8 + e], i3 = csr[k + 12 + e];
        uint v0 = *(const uint*)(base + (size_t)i0 * F_CAT);
        uint v1 = *(const uint*)(base + (size_t)i1 * F_CAT);
        uint v2 = *(const uint*)(base + (size_t)i2 * F_CAT);
        uint v3 = *(const uint*)(base + (size_t)i3 * F_CAT);
        a0 += bflo(v0); a1 += bfhi(v0);
        p0 += bflo(v1); p1 += bfhi(v1);
        q0 += bflo(v2); q1 += bfhi(v2);
        r0 += bflo(v3); r1 += bfhi(v3);
    }
    for (; k < ke; k += 4) {
        int kk = k + e;
        if (kk < ke) {
            uint v = *(const uint*)(base + (size_t)csr[kk] * F_CAT);
            a0 += bflo(v); a1 += bfhi(v);
        }
    }
    a0 += (p0 + q0) + r0;
    a1 += (p1 + q1) + r1;
}

// ---------------------------------------------------------------------------
// XCD-pinned layer-1 aggregation. 8 slices x 32 cols; slice s: dir = s>>2,
// cols dir*128 + (s&3)*32 .. +32 (3.2 MB sub-table -> fits per-XCD L2).
// Blocks drain queue q[xcc] first, then steal (correct under any mapping).
__global__ __launch_bounds__(256) void agg1_sliced(
        const ushort* __restrict__ linS, ushort* __restrict__ h1s,
        int* __restrict__ q,
        const ushort* __restrict__ csr_td, const int* __restrict__ off_td,
        const ushort* __restrict__ deg_td, const float* __restrict__ dinv_td,
        const ushort* __restrict__ csr_bu, const int* __restrict__ off_bu,
        const ushort* __restrict__ deg_bu, const float* __restrict__ dinv_bu,
        const float* __restrict__ b_td, const float* __restrict__ b_bu) {
    int xcc = get_xcc();
    int tid = threadIdx.x;
    int wave = tid >> 6, lane = tid & 63;
    int e = lane >> 4, c = lane & 15;
    __shared__ int chunk_s;
    for (int pass = 0; pass < 8; pass++) {
        int slice = (xcc + pass) & 7;
        int dir = slice >> 2;
        const ushort* csr = dir ? csr_bu : csr_td;
        const int* off    = dir ? off_bu : off_td;
        const ushort* deg = dir ? deg_bu : deg_td;
        const float* dinv = dir ? dinv_bu : dinv_td;
        const float* bias = dir ? b_bu : b_td;
        int colbase = dir * F_H + (slice & 3) * 32;
        const ushort* base = linS + colbase + c * 2;
        int bc = (slice & 3) * 32 + c * 2;
        float bs0 = bias[bc], bs1 = bias[bc + 1];
        while (true) {
            __syncthreads();
            if (tid == 0) chunk_s = atomicAdd(&q[slice], 1);
            __syncthreads();
            int chunk = chunk_s;
            if (chunk >= NCHUNK) break;
            int ns = chunk * CHUNK + wave * 64;
            int ne = ns + 64 < N_NODES ? ns + 64 : N_NODES;
            for (int n = ns; n < ne; n++) {
                float a0 = 0.f, a1 = 0.f;
                int kb = off[n];
                gather32(base, csr, kb, kb + deg[n], e, a0, a1);
                a0 += __shfl_xor(a0, 16); a1 += __shfl_xor(a1, 16);
                a0 += __shfl_xor(a0, 32); a1 += __shfl_xor(a1, 32);
                uint vs = *(const uint*)(base + (size_t)n * F_CAT);  // self
                a0 += bflo(vs); a1 += bfhi(vs);
                float dn = dinv[n];
                float o0 = fmaxf(a0 * dn + bs0, 0.f) * dn;  // dinv pre-folded
                float o1 = fmaxf(a1 * dn + bs1, 0.f) * dn;
                if (e == 0) {
                    uint pk = (uint)f2bf(o0) | ((uint)f2bf(o1) << 16);
                    *(uint*)(h1s + (size_t)n * F_CAT + colbase + c * 2) = pk;
                }
            }
        }
    }
}

// ---------------------------------------------------------------------------
// XCD-pinned layer-2 aggregation + pool (pool-before-W2):
// pooled_pre[g, col] += dn*(self + neigh). Sorted batch -> per-wave segment
// accumulate over 64 consecutive nodes, atomic flush at boundaries.
__global__ __launch_bounds__(256) void agg2_sliced(
        const ushort* __restrict__ h1s, float* __restrict__ pooled_pre,
        int* __restrict__ q, const int* __restrict__ batch,
        const ushort* __restrict__ csr_td, const int* __restrict__ off_td,
        const ushort* __restrict__ deg_td, const float* __restrict__ dinv_td,
        const ushort* __restrict__ csr_bu, const int* __restrict__ off_bu,
        const ushort* __restrict__ deg_bu, const float* __restrict__ dinv_bu) {
    int xcc = get_xcc();
    int tid = threadIdx.x;
    int wave = tid >> 6, lane = tid & 63;
    int e = lane >> 4, c = lane & 15;
    __shared__ int chunk_s;
    for (int pass = 0; pass < 8; pass++) {
        int slice = (xcc + pass) & 7;
        int dir = slice >> 2;
        const ushort* csr = dir ? csr_bu : csr_td;
        const int* off    = dir ? off_bu : off_td;
        const ushort* deg = dir ? deg_bu : deg_td;
        const float* dinv = dir ? dinv_bu : dinv_td;
        int colbase = dir * F_H + (slice & 3) * 32;
        const ushort* base = h1s + colbase + c * 2;
        float* pp = pooled_pre + colbase + c * 2;
        while (true) {
            __syncthreads();
            if (tid == 0) chunk_s = atomicAdd(&q[8 + slice], 1);
            __syncthreads();
            int chunk = chunk_s;
            if (chunk >= NCHUNK) break;
            int ns = chunk * CHUNK + wave * 64;
            int ne = ns + 64 < N_NODES ? ns + 64 : N_NODES;
            if (ns < ne) {
                int gc = batch[ns];
                float acc0 = 0.f, acc1 = 0.f;
                for (int n = ns; n < ne; n++) {
                    int g = batch[n];
                    if (g != gc) {  // wave-uniform
                        if (e == 0) {
                            unsafeAtomicAdd(pp + (size_t)gc * F_CAT, acc0);
                            unsafeAtomicAdd(pp + (size_t)gc * F_CAT + 1, acc1);
                        }
                        acc0 = acc1 = 0.f;
                        gc = g;
                    }
                    float a0 = 0.f, a1 = 0.f;
                    int kb = off[n];
                    gather32(base, csr, kb, kb + deg[n], e, a0, a1);
                    a0 += __shfl_xor(a0, 16); a1 += __shfl_xor(a1, 16);
                    a0 += __shfl_xor(a0, 32); a1 += __shfl_xor(a1, 32);
                    uint vs = *(const uint*)(base + (size_t)n * F_CAT);
                    a0 += bflo(vs); a1 += bfhi(vs);
                    float dn = dinv[n];
                    acc0 += a0 * dn;
                    acc1 += a1 * dn;
                }
                if (e == 0) {
                    unsafeAtomicAdd(pp + (size_t)gc * F_CAT, acc0);
                    unsafeAtomicAdd(pp + (size_t)gc * F_CAT + 1, acc1);
                }
            }
        }
    }
}

// ---------------------------------------------------------------------------
// Head: z = pooled_pre @ W2 (per branch) + cnt*b2 in concat([bu,td]) order,
// then MLP relu(z@pw1+pb1)@pw2+pb2. One block per graph.
__global__ __launch_bounds__(256) void head_kernel(
        const float* __restrict__ pooled_pre, const int* __restrict__ batch,
        const ushort* __restrict__ Wt2,
        const float* __restrict__ td_b2, const float* __restrict__ bu_b2,
        const float* __restrict__ pw1, const float* __restrict__ pb1,
        const float* __restrict__ pw2, const float* __restrict__ pb2,
        float* __restrict__ out) {
    int g = blockIdx.x;
    int tid = threadIdx.x;
    __shared__ float row[256], z[256], hid[256];
    row[tid] = pooled_pre[(size_t)g * 256 + tid];
    int lo = 0, hi = N_NODES;
    while (lo < hi) { int m = (lo + hi) >> 1; if (batch[m] < g) lo = m + 1; else hi = m; }
    int start = lo;
    lo = start; hi = N_NODES;
    while (lo < hi) { int m = (lo + hi) >> 1; if (batch[m] < g + 1) lo = m + 1; else hi = m; }
    float cnt = (float)(lo - start);
    __syncthreads();
    const float* rsel = (tid < 128) ? (row + F_H) : row;
    float b2 = (tid < 128) ? bu_b2[tid] : td_b2[tid - F_H];
    float acc = cnt * b2;
    for (int k = 0; k < F_H; k++) acc += rsel[k] * bfu(Wt2[(size_t)k * 256 + tid]);
    z[tid] = acc;
    __syncthreads();
    float h = pb1[tid];
    for (int k = 0; k < 256; k++) h += z[k] * pw1[(size_t)k * 256 + tid];
    hid[tid] = fmaxf(h, 0.f);
    __syncthreads();
    if (tid < 128) {
        float o = pb2[tid];
        for (int k = 0; k < 256; k++) o += hid[k] * pw2[(size_t)k * 128 + tid];
        out[(size_t)g * 128 + tid] = o;
    }
}

// ---------------------------------------------------------------------------
extern "C" void kernel_launch(void* const* d_in, const int* in_sizes, int n_in,
                              void* d_out, int out_size, void* d_ws, size_t ws_size,
                              hipStream_t stream) {
    const float* x     = (const float*)d_in[0];
    const int*   ei    = (const int*)d_in[1];
    const int*   batch = (const int*)d_in[2];
    const float* td_W1 = (const float*)d_in[4];
    const float* td_b1 = (const float*)d_in[5];
    const float* td_W2 = (const float*)d_in[6];
    const float* td_b2 = (const float*)d_in[7];
    const float* bu_W1 = (const float*)d_in[8];
    const float* bu_b1 = (const float*)d_in[9];
    const float* bu_W2 = (const float*)d_in[10];
    const float* bu_b2 = (const float*)d_in[11];
    const float* pw1   = (const float*)d_in[12];
    const float* pb1   = (const float*)d_in[13];
    const float* pw2   = (const float*)d_in[14];
    const float* pb2   = (const float*)d_in[15];
    float* out = (float*)d_out;

    // ---- workspace carve ----
    char* p = (char*)d_ws;
    auto alloc = [&](size_t bytes) { void* r = (void*)p; p += (bytes + 255) & ~(size_t)255; return r; };
    // single memset region: gcur (1 KB) | queues (16 ints) | pooled_pre
    char* zreg = (char*)alloc(2048 + (size_t)N_GRAPHS * F_CAT * sizeof(float));
    int* gcur = (int*)zreg;
    int* q    = (int*)(zreg + 1024);
    float* pooled_pre = (float*)(zreg + 2048);
    uint* ebuf_td = (uint*)alloc((size_t)NB * CAP * sizeof(uint));
    uint* ebuf_bu = (uint*)alloc((size_t)NB * CAP * sizeof(uint));
    ushort* csr_td = (ushort*)alloc((size_t)NB * CAP * sizeof(ushort));
    ushort* csr_bu = (ushort*)alloc((size_t)NB * CAP * sizeof(ushort));
    int* off_td = (int*)alloc((size_t)N_NODES * sizeof(int));
    int* off_bu = (int*)alloc((size_t)N_NODES * sizeof(int));
    ushort* deg_td = (ushort*)alloc((size_t)N_NODES * sizeof(ushort));
    ushort* deg_bu = (ushort*)alloc((size_t)N_NODES * sizeof(ushort));
    float* dinv_td = (float*)alloc((size_t)N_PAD * sizeof(float));
    float* dinv_bu = (float*)alloc((size_t)N_PAD * sizeof(float));
    ushort* Bt1 = (ushort*)alloc((size_t)256 * 256 * sizeof(ushort));
    ushort* Wt2 = (ushort*)alloc((size_t)128 * 256 * sizeof(ushort));
    ushort* xb   = (ushort*)alloc((size_t)N_PAD * F_CAT * sizeof(ushort));
    ushort* linb = (ushort*)alloc((size_t)N_PAD * F_CAT * sizeof(ushort));
    ushort* h1s  = (ushort*)alloc((size_t)N_PAD * F_CAT * sizeof(ushort));

    hipMemsetAsync(zreg, 0, 2048 + (size_t)N_GRAPHS * F_CAT * sizeof(float), stream);

    // ---- graph structure (bucketed counting sort) ----
    csr_scatter_kernel<<<N_EDGES / EPB, 256, 0, stream>>>(ei, gcur, ebuf_td, ebuf_bu);
    csr_build_kernel<<<dim3(NB, 2), 256, 0, stream>>>(ebuf_td, ebuf_bu, gcur,
        off_td, off_bu, deg_td, deg_bu, dinv_td, dinv_bu, csr_td, csr_bu);

    // ---- bf16 conversions ----
    cvt_x_kernel<<<(N_PAD * F_IN / 4) / 256, 256, 0, stream>>>(x, xb);
    prep_w_kernel<<<256, 256, 0, stream>>>(td_W1, bu_W1, td_W2, bu_W2, Bt1, Wt2);

    // ---- layer 1: GEMM + XCD-pinned aggregation ----
    dim3 gg(N_PAD / 128, 2);
    gemm_mfma<<<gg, 256, 0, stream>>>(xb, Bt1, linb, dinv_td, dinv_bu);
    agg1_sliced<<<1024, 256, 0, stream>>>(linb, h1s, q,
        csr_td, off_td, deg_td, dinv_td, csr_bu, off_bu, deg_bu, dinv_bu, td_b1, bu_b1);

    // ---- layer 2: XCD-pinned aggregation + pool ----
    agg2_sliced<<<1024, 256, 0, stream>>>(h1s, pooled_pre, q, batch,
        csr_td, off_td, deg_td, dinv_td, csr_bu, off_bu, deg_bu, dinv_bu);

    // ---- head: W2 matvec + cnt*b2 + MLP ----
    head_kernel<<<N_GRAPHS, 256, 0, stream>>>(pooled_pre, batch, Wt2,
        td_b2, bu_b2, pw1, pb1, pw2, pb2, out);
}

// Round 10
// 410.259 us; speedup vs baseline: 2.2576x; 2.2576x over previous
//
#include <hip/hip_runtime.h>

#define N_NODES 50000
#define N_PAD   50048   // 391*128, GEMM epilogue needs no row guards
#define N_EDGES 800000
#define N_GRAPHS 512
#define F_IN 256
#define F_H 128
#define F_CAT 256

// bucketed CSR build
#define BSHIFT 9
#define NB 98           // ceil(50000/512) buckets
#define CAP 10240       // edge capacity per bucket (mean 8163, 23 sigma slack)
#define EPB 3125        // edges per scatter block (256 blocks)
#define GEMM_BLOCKS 782 // 391 row-tiles x 2 col-tiles

typedef __attribute__((ext_vector_type(8))) short short8;
typedef __attribute__((ext_vector_type(4))) float f32x4;
typedef unsigned int uint;
typedef unsigned short ushort;

static __device__ __forceinline__ ushort f2bf(float f) {
    uint u = __float_as_uint(f);
    u += 0x7FFF + ((u >> 16) & 1);  // RNE
    return (ushort)(u >> 16);
}
static __device__ __forceinline__ float bflo(uint v) { return __uint_as_float(v << 16); }
static __device__ __forceinline__ float bfhi(uint v) { return __uint_as_float(v & 0xFFFF0000u); }
static __device__ __forceinline__ float bfu(ushort v) { return __uint_as_float((uint)v << 16); }

// async global->LDS, 16B per lane; lds base must be wave-uniform
#define GLL(g, l) __builtin_amdgcn_global_load_lds( \
    (const __attribute__((address_space(1))) unsigned int*)(g), \
    (__attribute__((address_space(3))) unsigned int*)(l), 16, 0, 0)

// ---------------------------------------------------------------------------
// Degree counts (cnt arrays zeroed by the memset region). Runs BEFORE the
// fused GEMM so dinv is valid in the GEMM epilogue.
__global__ __launch_bounds__(256) void deg_kernel(const int* __restrict__ ei,
                                                  int* __restrict__ cnt_td,
                                                  int* __restrict__ cnt_bu) {
    int i = blockIdx.x * 256 + threadIdx.x;
    if (i < N_EDGES) {
        int s = ei[i], d = ei[N_EDGES + i];
        atomicAdd(&cnt_td[d], 1);
        atomicAdd(&cnt_bu[s], 1);
    }
}

// dinv = rsqrt(deg+1), padded rows get 1.0 (multiplied by zero rows anyway)
__global__ __launch_bounds__(256) void dinv_kernel(const int* __restrict__ cnt_td,
                                                   const int* __restrict__ cnt_bu,
                                                   float* __restrict__ dinv_td,
                                                   float* __restrict__ dinv_bu) {
    int i = blockIdx.x * 256 + threadIdx.x;
    if (i < N_PAD) {
        int ct = (i < N_NODES) ? cnt_td[i] : 0;
        int cb = (i < N_NODES) ? cnt_bu[i] : 0;
        dinv_td[i] = rsqrtf((float)ct + 1.0f);
        dinv_bu[i] = rsqrtf((float)cb + 1.0f);
    }
}

// ---------------------------------------------------------------------------
// Fused kernel: blocks [0, GEMM_BLOCKS) run the layer-1 MFMA GEMM
// (A = x f32 converted in-flight, C = linb bf16 row-scaled by branch dinv —
// dinv valid because deg/dinv kernels ran first); blocks [GEMM_BLOCKS, +256)
// run the edge bucket-scatter. gcur RELATIVE (zeroed by memset).
__global__ __launch_bounds__(256) void gemm_scatter_kernel(
        const float* __restrict__ x, const ushort* __restrict__ Bt,
        ushort* __restrict__ C,
        const float* __restrict__ dinv_td, const float* __restrict__ dinv_bu,
        const int* __restrict__ ei, int* __restrict__ gcur,
        uint* __restrict__ ebuf_td, uint* __restrict__ ebuf_bu) {
    __shared__ __align__(16) ushort As[128 * 32];
    __shared__ __align__(16) ushort Bs[128 * 32];
    __shared__ int lcnt[256];
    __shared__ int lbase[256];
    int tid = threadIdx.x;

    if (blockIdx.x < GEMM_BLOCKS) {
        // ---------------- GEMM part ----------------
        int wave = tid >> 6, lane = tid & 63, quad = lane >> 4, l16 = lane & 15;
        size_t bm = (size_t)(blockIdx.x >> 1) * 128;
        int bnt = blockIdx.x & 1;
        size_t bn = (size_t)bnt * 128;
        const float* dsel = bnt ? dinv_bu : dinv_td;

        f32x4 acc[2][8];
        const f32x4 z4 = {0.f, 0.f, 0.f, 0.f};
#pragma unroll
        for (int i = 0; i < 2; i++)
#pragma unroll
            for (int j = 0; j < 8; j++) acc[i][j] = z4;

        // A staging (f32 -> bf16 in regs): thread covers rows ar+32j, kcols akq..+3
        int ar = tid >> 3;          // 0..31
        int akq = (tid & 7) * 4;    // 0..28
        // B staging via GLL: 512 x 16B chunks, 2 per thread
        int cb0 = wave * 64;
        int cb1 = 256 + wave * 64;
        int c0 = cb0 + lane, c1 = cb1 + lane;
        int r0 = c0 >> 2, s0 = (c0 & 3) * 8;
        int r1 = c1 >> 2, s1 = (c1 & 3) * 8;
        const ushort* b0p = Bt + (bn + r0) * 256 + s0;
        const ushort* b1p = Bt + (bn + r1) * 256 + s1;
        ushort* lB0 = Bs + cb0 * 8;
        ushort* lB1 = Bs + cb1 * 8;

        for (int kb = 0; kb < 8; kb++) {
            int k0 = kb * 32;
            float4 av[4];
#pragma unroll
            for (int j = 0; j < 4; j++) {
                size_t grow = bm + ar + j * 32;
                if (grow < N_NODES)
                    av[j] = *(const float4*)(x + grow * F_IN + k0 + akq);
                else
                    av[j] = make_float4(0.f, 0.f, 0.f, 0.f);
            }
            __syncthreads();  // previous iter's fragment reads done
            GLL(b0p + k0, lB0);
            GLL(b1p + k0, lB1);
#pragma unroll
            for (int j = 0; j < 4; j++) {
                ushort4 u;
                u.x = f2bf(av[j].x); u.y = f2bf(av[j].y);
                u.z = f2bf(av[j].z); u.w = f2bf(av[j].w);
                *(ushort4*)(As + (ar + j * 32) * 32 + akq) = u;
            }
            __syncthreads();  // drains vmcnt + lgkm, tiles ready
            short8 af0 = *(const short8*)(As + (wave * 32 + l16) * 32 + quad * 8);
            short8 af1 = *(const short8*)(As + (wave * 32 + 16 + l16) * 32 + quad * 8);
#pragma unroll
            for (int ct = 0; ct < 8; ct++) {
                short8 bfr = *(const short8*)(Bs + (ct * 16 + l16) * 32 + quad * 8);
                acc[0][ct] = __builtin_amdgcn_mfma_f32_16x16x32_bf16(af0, bfr, acc[0][ct], 0, 0, 0);
                acc[1][ct] = __builtin_amdgcn_mfma_f32_16x16x32_bf16(af1, bfr, acc[1][ct], 0, 0, 0);
            }
        }
#pragma unroll
        for (int rt = 0; rt < 2; rt++) {
#pragma unroll
            for (int r = 0; r < 4; r++) {
                size_t row = bm + wave * 32 + rt * 16 + quad * 4 + r;
                float dv = dsel[row];
#pragma unroll
                for (int ct = 0; ct < 8; ct++) {
                    C[row * 256 + bn + ct * 16 + l16] = f2bf(acc[rt][ct][r] * dv);
                }
            }
        }
    } else {
        // ---------------- bucket-scatter part ----------------
        lcnt[tid] = 0;
        __syncthreads();
        int e0 = (blockIdx.x - GEMM_BLOCKS) * EPB;
        for (int k = tid; k < EPB; k += 256) {
            int i = e0 + k;
            int s = ei[i], d = ei[N_EDGES + i];
            atomicAdd(&lcnt[d >> BSHIFT], 1);
            atomicAdd(&lcnt[128 + (s >> BSHIFT)], 1);
        }
        __syncthreads();
        if (tid < 2 * NB) {
            int dir = tid / NB, b = tid % NB;
            int c = lcnt[dir * 128 + b];
            lbase[dir * 128 + b] = c ? atomicAdd(&gcur[dir * NB + b], c) : 0;
        }
        __syncthreads();
        lcnt[tid] = 0;
        __syncthreads();
        for (int k = tid; k < EPB; k += 256) {
            int i = e0 + k;
            int s = ei[i], d = ei[N_EDGES + i];
            int bd = d >> BSHIFT, bs = s >> BSHIFT;
            int p = atomicAdd(&lcnt[bd], 1) + lbase[bd];
            ebuf_td[(size_t)bd * CAP + p] = (uint)s | ((uint)(d & 511) << 16);
            int q = atomicAdd(&lcnt[128 + bs], 1) + lbase[128 + bs];
            ebuf_bu[(size_t)bs * CAP + q] = (uint)d | ((uint)(s & 511) << 16);
        }
    }
}

// ---------------------------------------------------------------------------
// S2: per-(bucket,dir) CSR build, bucket-local scatter window (dinv done upstream)
__global__ __launch_bounds__(256) void csr_build_kernel(
        const uint* __restrict__ ebuf_td, const uint* __restrict__ ebuf_bu,
        const int* __restrict__ gcur,
        int* off_td, int* off_bu, ushort* deg_td, ushort* deg_bu,
        ushort* csr_td, ushort* csr_bu) {
    int b = blockIdx.x, dir = blockIdx.y;
    const uint* ebuf = dir ? ebuf_bu : ebuf_td;
    int* off     = dir ? off_bu : off_td;
    ushort* deg  = dir ? deg_bu : deg_td;
    ushort* csr  = dir ? csr_bu : csr_td;
    __shared__ int cntL[512], offL[512], sm[256];
    int tid = threadIdx.x;
    cntL[tid] = 0; cntL[tid + 256] = 0;
    __syncthreads();
    int rbeg = b * CAP;
    int rend = rbeg + gcur[dir * NB + b];
    for (int k = rbeg + tid; k < rend; k += 256)
        atomicAdd(&cntL[ebuf[k] >> 16], 1);
    __syncthreads();
    int a0 = cntL[tid * 2], a1 = cntL[tid * 2 + 1];
    int ps = a0 + a1;
    sm[tid] = ps;
    __syncthreads();
    for (int o = 1; o < 256; o <<= 1) {
        int u = (tid >= o) ? sm[tid - o] : 0;
        __syncthreads();
        sm[tid] += u;
        __syncthreads();
    }
    int excl = sm[tid] - ps;
    offL[tid * 2] = excl;
    offL[tid * 2 + 1] = excl + a0;
    __syncthreads();
    int nbase = b << BSHIFT;
#pragma unroll
    for (int j = 0; j < 2; j++) {
        int nloc = tid + j * 256;
        int n = nbase + nloc;
        if (n < N_NODES) {
            off[n] = rbeg + offL[nloc];
            deg[n] = (ushort)cntL[nloc];
        }
    }
    cntL[tid] = offL[tid];
    cntL[tid + 256] = offL[tid + 256];
    __syncthreads();
    for (int k = rbeg + tid; k < rend; k += 256) {
        uint e = ebuf[k];
        int slot = atomicAdd(&cntL[e >> 16], 1);
        csr[rbeg + slot] = (ushort)(e & 0xFFFF);
    }
}

// ---------------------------------------------------------------------------
// Bt1[n][k]; Wt2[k][c] with c in concat([bu, td]) order.
__global__ void prep_w_kernel(const float* __restrict__ td_W1, const float* __restrict__ bu_W1,
                              const float* __restrict__ td_W2, const float* __restrict__ bu_W2,
                              ushort* __restrict__ Bt1, ushort* __restrict__ Wt2) {
    int n = blockIdx.x;   // 0..255
    int k = threadIdx.x;  // 0..255
    float w1 = (n < F_H) ? td_W1[(size_t)k * F_H + n] : bu_W1[(size_t)k * F_H + (n - F_H)];
    Bt1[(size_t)n * 256 + k] = f2bf(w1);
    if (k < 128) {
        float w2 = (n < F_H) ? bu_W2[(size_t)k * F_H + n]
                             : td_W2[(size_t)k * F_H + (n - F_H)];
        Wt2[(size_t)k * 256 + n] = f2bf(w2);
    }
}

// ---------------------------------------------------------------------------
// Wave-gather: lane = half*32 + l32; l32 covers 4 cols (uint2), half selects
// one of 2 concurrent edge rows. Unroll-8 -> 16 edges in flight per wave.
static __device__ __forceinline__ void gather_node(
        const ushort* __restrict__ base, const ushort* __restrict__ csr,
        int kb, int ke, int half, float a[4]) {
    float p[4] = {0.f, 0.f, 0.f, 0.f};
    float q[4] = {0.f, 0.f, 0.f, 0.f};
    float r[4] = {0.f, 0.f, 0.f, 0.f};
    int k = kb;
    for (; k + 16 <= ke; k += 16) {
        int i0 = csr[k + half],      i1 = csr[k + 2 + half];
        int i2 = csr[k + 4 + half],  i3 = csr[k + 6 + half];
        int i4 = csr[k + 8 + half],  i5 = csr[k + 10 + half];
        int i6 = csr[k + 12 + half], i7 = csr[k + 14 + half];
        uint2 v0 = *(const uint2*)(base + (size_t)i0 * F_CAT);
        uint2 v1 = *(const uint2*)(base + (size_t)i1 * F_CAT);
        uint2 v2 = *(const uint2*)(base + (size_t)i2 * F_CAT);
        uint2 v3 = *(const uint2*)(base + (size_t)i3 * F_CAT);
        uint2 v4 = *(const uint2*)(base + (size_t)i4 * F_CAT);
        uint2 v5 = *(const uint2*)(base + (size_t)i5 * F_CAT);
        uint2 v6 = *(const uint2*)(base + (size_t)i6 * F_CAT);
        uint2 v7 = *(const uint2*)(base + (size_t)i7 * F_CAT);
        a[0] += bflo(v0.x); a[1] += bfhi(v0.x); a[2] += bflo(v0.y); a[3] += bfhi(v0.y);
        p[0] += bflo(v1.x); p[1] += bfhi(v1.x); p[2] += bflo(v1.y); p[3] += bfhi(v1.y);
        q[0] += bflo(v2.x); q[1] += bfhi(v2.x); q[2] += bflo(v2.y); q[3] += bfhi(v2.y);
        r[0] += bflo(v3.x); r[1] += bfhi(v3.x); r[2] += bflo(v3.y); r[3] += bfhi(v3.y);
        a[0] += bflo(v4.x); a[1] += bfhi(v4.x); a[2] += bflo(v4.y); a[3] += bfhi(v4.y);
        p[0] += bflo(v5.x); p[1] += bfhi(v5.x); p[2] += bflo(v5.y); p[3] += bfhi(v5.y);
        q[0] += bflo(v6.x); q[1] += bfhi(v6.x); q[2] += bflo(v6.y); q[3] += bfhi(v6.y);
        r[0] += bflo(v7.x); r[1] += bfhi(v7.x); r[2] += bflo(v7.y); r[3] += bfhi(v7.y);
    }
    for (; k + 8 <= ke; k += 8) {
        int i0 = csr[k + half],     i1 = csr[k + 2 + half];
        int i2 = csr[k + 4 + half], i3 = csr[k + 6 + half];
        uint2 v0 = *(const uint2*)(base + (size_t)i0 * F_CAT);
        uint2 v1 = *(const uint2*)(base + (size_t)i1 * F_CAT);
        uint2 v2 = *(const uint2*)(base + (size_t)i2 * F_CAT);
        uint2 v3 = *(const uint2*)(base + (size_t)i3 * F_CAT);
        a[0] += bflo(v0.x); a[1] += bfhi(v0.x); a[2] += bflo(v0.y); a[3] += bfhi(v0.y);
        p[0] += bflo(v1.x); p[1] += bfhi(v1.x); p[2] += bflo(v1.y); p[3] += bfhi(v1.y);
        q[0] += bflo(v2.x); q[1] += bfhi(v2.x); q[2] += bflo(v2.y); q[3] += bfhi(v2.y);
        r[0] += bflo(v3.x); r[1] += bfhi(v3.x); r[2] += bflo(v3.y); r[3] += bfhi(v3.y);
    }
    for (; k < ke; k += 2) {
        int kk = k + half;
        if (kk < ke) {
            uint2 v = *(const uint2*)(base + (size_t)csr[kk] * F_CAT);
            a[0] += bflo(v.x); a[1] += bfhi(v.x); a[2] += bflo(v.y); a[3] += bfhi(v.y);
        }
    }
#pragma unroll
    for (int j = 0; j < 4; j++) a[j] += (p[j] + q[j]) + r[j];
}

// ---------------------------------------------------------------------------
// Layer-1 aggregation. Wave handles 8 consecutive nodes of one branch.
// h1s[n] = relu(dn*(self+neigh) + b1) * dn   (dinv pre-folded for layer 2)
__global__ __launch_bounds__(256) void agg1_kernel(
        const ushort* __restrict__ linS, ushort* __restrict__ h1s,
        const ushort* __restrict__ csr_td, const int* __restrict__ off_td,
        const ushort* __restrict__ deg_td, const float* __restrict__ dinv_td,
        const ushort* __restrict__ csr_bu, const int* __restrict__ off_bu,
        const ushort* __restrict__ deg_bu, const float* __restrict__ dinv_bu,
        const float* __restrict__ b_td, const float* __restrict__ b_bu) {
    int wave = threadIdx.x >> 6, lane = threadIdx.x & 63;
    int n0 = (blockIdx.x * 2 + (wave >> 1)) * 8;
    int br = wave & 1;
    const ushort* csr = br ? csr_bu : csr_td;
    const int* off    = br ? off_bu : off_td;
    const ushort* deg = br ? deg_bu : deg_td;
    const float* dinv = br ? dinv_bu : dinv_td;
    const float* bias = br ? b_bu : b_td;
    int half = lane >> 5, l32 = lane & 31;
    int col = br * F_H + l32 * 4;
    const ushort* base = linS + col;
    int bcol = l32 * 4;
    float bs0 = bias[bcol], bs1 = bias[bcol + 1];
    float bs2 = bias[bcol + 2], bs3 = bias[bcol + 3];

#pragma unroll
    for (int j = 0; j < 8; j++) {
        int n = n0 + j;
        float a[4] = {0.f, 0.f, 0.f, 0.f};
        int kb = off[n];
        gather_node(base, csr, kb, kb + deg[n], half, a);
#pragma unroll
        for (int t = 0; t < 4; t++) a[t] += __shfl_xor(a[t], 32);
        uint2 vs = *(const uint2*)(base + (size_t)n * F_CAT);  // self
        a[0] += bflo(vs.x); a[1] += bfhi(vs.x); a[2] += bflo(vs.y); a[3] += bfhi(vs.y);
        float dn = dinv[n];
        float o0 = fmaxf(a[0] * dn + bs0, 0.f) * dn;
        float o1 = fmaxf(a[1] * dn + bs1, 0.f) * dn;
        float o2 = fmaxf(a[2] * dn + bs2, 0.f) * dn;
        float o3 = fmaxf(a[3] * dn + bs3, 0.f) * dn;
        if (half == 0) {
            uint2 pk;
            pk.x = (uint)f2bf(o0) | ((uint)f2bf(o1) << 16);
            pk.y = (uint)f2bf(o2) | ((uint)f2bf(o3) << 16);
            *(uint2*)(h1s + (size_t)n * F_CAT + col) = pk;
        }
    }
}

// ---------------------------------------------------------------------------
// Layer-2 aggregation fused with pooling (pool-before-W2 algebra):
// pooled_pre[g, col] += dn*(self + neigh) over nodes of graph g.
__global__ __launch_bounds__(256) void agg2_pool_kernel(
        const ushort* __restrict__ h1s, float* __restrict__ pooled_pre,
        const int* __restrict__ batch,
        const ushort* __restrict__ csr_td, const int* __restrict__ off_td,
        const ushort* __restrict__ deg_td, const float* __restrict__ dinv_td,
        const ushort* __restrict__ csr_bu, const int* __restrict__ off_bu,
        const ushort* __restrict__ deg_bu, const float* __restrict__ dinv_bu) {
    int wave = threadIdx.x >> 6, lane = threadIdx.x & 63;
    int n0 = (blockIdx.x * 2 + (wave >> 1)) * 8;
    int br = wave & 1;
    const ushort* csr = br ? csr_bu : csr_td;
    const int* off    = br ? off_bu : off_td;
    const ushort* deg = br ? deg_bu : deg_td;
    const float* dinv = br ? dinv_bu : dinv_td;
    int half = lane >> 5, l32 = lane & 31;
    int col = br * F_H + l32 * 4;
    const ushort* base = h1s + col;

    float acc0 = 0.f, acc1 = 0.f, acc2 = 0.f, acc3 = 0.f;
    int gcur = batch[n0];
#pragma unroll
    for (int j = 0; j < 8; j++) {
        int n = n0 + j;
        int g = batch[n];
        if (g != gcur) {  // wave-uniform
            if (half == 0) {
                float* pp = &pooled_pre[(size_t)gcur * F_CAT + col];
                unsafeAtomicAdd(pp,     acc0);
                unsafeAtomicAdd(pp + 1, acc1);
                unsafeAtomicAdd(pp + 2, acc2);
                unsafeAtomicAdd(pp + 3, acc3);
            }
            acc0 = acc1 = acc2 = acc3 = 0.f;
            gcur = g;
        }
        float a[4] = {0.f, 0.f, 0.f, 0.f};
        int kb = off[n];
        gather_node(base, csr, kb, kb + deg[n], half, a);
#pragma unroll
        for (int t = 0; t < 4; t++) a[t] += __shfl_xor(a[t], 32);
        uint2 vs = *(const uint2*)(base + (size_t)n * F_CAT);
        a[0] += bflo(vs.x); a[1] += bfhi(vs.x); a[2] += bflo(vs.y); a[3] += bfhi(vs.y);
        float dn = dinv[n];
        acc0 += a[0] * dn;
        acc1 += a[1] * dn;
        acc2 += a[2] * dn;
        acc3 += a[3] * dn;
    }
    if (half == 0) {
        float* pp = &pooled_pre[(size_t)gcur * F_CAT + col];
        unsafeAtomicAdd(pp,     acc0);
        unsafeAtomicAdd(pp + 1, acc1);
        unsafeAtomicAdd(pp + 2, acc2);
        unsafeAtomicAdd(pp + 3, acc3);
    }
}

// ---------------------------------------------------------------------------
// Head: z = pooled_pre @ W2 (per branch) + cnt*b2 in concat([bu,td]) order,
// then MLP relu(z@pw1+pb1)@pw2+pb2. One block per graph.
__global__ __launch_bounds__(256) void head_kernel(
        const float* __restrict__ pooled_pre, const int* __restrict__ batch,
        const ushort* __restrict__ Wt2,
        const float* __restrict__ td_b2, const float* __restrict__ bu_b2,
        const float* __restrict__ pw1, const float* __restrict__ pb1,
        const float* __restrict__ pw2, const float* __restrict__ pb2,
        float* __restrict__ out) {
    int g = blockIdx.x;
    int tid = threadIdx.x;
    __shared__ float row[256], z[256], hid[256];
    row[tid] = pooled_pre[(size_t)g * 256 + tid];
    int lo = 0, hi = N_NODES;
    while (lo < hi) { int m = (lo + hi) >> 1; if (batch[m] < g) lo = m + 1; else hi = m; }
    int start = lo;
    lo = start; hi = N_NODES;
    while (lo < hi) { int m = (lo + hi) >> 1; if (batch[m] < g + 1) lo = m + 1; else hi = m; }
    float cnt = (float)(lo - start);
    __syncthreads();
    const float* rsel = (tid < 128) ? (row + F_H) : row;
    float b2 = (tid < 128) ? bu_b2[tid] : td_b2[tid - F_H];
    float acc = cnt * b2;
    for (int k = 0; k < F_H; k++) acc += rsel[k] * bfu(Wt2[(size_t)k * 256 + tid]);
    z[tid] = acc;
    __syncthreads();
    float h = pb1[tid];
    for (int k = 0; k < 256; k++) h += z[k] * pw1[(size_t)k * 256 + tid];
    hid[tid] = fmaxf(h, 0.f);
    __syncthreads();
    if (tid < 128) {
        float o = pb2[tid];
        for (int k = 0; k < 256; k++) o += hid[k] * pw2[(size_t)k * 128 + tid];
        out[(size_t)g * 128 + tid] = o;
    }
}

// ---------------------------------------------------------------------------
extern "C" void kernel_launch(void* const* d_in, const int* in_sizes, int n_in,
                              void* d_out, int out_size, void* d_ws, size_t ws_size,
                              hipStream_t stream) {
    const float* x     = (const float*)d_in[0];
    const int*   ei    = (const int*)d_in[1];
    const int*   batch = (const int*)d_in[2];
    const float* td_W1 = (const float*)d_in[4];
    const float* td_b1 = (const float*)d_in[5];
    const float* td_W2 = (const float*)d_in[6];
    const float* td_b2 = (const float*)d_in[7];
    const float* bu_W1 = (const float*)d_in[8];
    const float* bu_b1 = (const float*)d_in[9];
    const float* bu_W2 = (const float*)d_in[10];
    const float* bu_b2 = (const float*)d_in[11];
    const float* pw1   = (const float*)d_in[12];
    const float* pb1   = (const float*)d_in[13];
    const float* pw2   = (const float*)d_in[14];
    const float* pb2   = (const float*)d_in[15];
    float* out = (float*)d_out;

    // ---- workspace carve ----
    char* p = (char*)d_ws;
    auto alloc = [&](size_t bytes) { void* r = (void*)p; p += (bytes + 255) & ~(size_t)255; return r; };
    // single memset region: gcur (1 KB) | pooled_pre (512 KB) | cnt_td/cnt_bu (400 KB)
    size_t zsz = 1024 + (size_t)N_GRAPHS * F_CAT * sizeof(float) + (size_t)2 * N_NODES * sizeof(int);
    char* zreg = (char*)alloc(zsz);
    int* gcur = (int*)zreg;
    float* pooled_pre = (float*)(zreg + 1024);
    int* cnt_td = (int*)(zreg + 1024 + (size_t)N_GRAPHS * F_CAT * sizeof(float));
    int* cnt_bu = cnt_td + N_NODES;
    uint* ebuf_td = (uint*)alloc((size_t)NB * CAP * sizeof(uint));
    uint* ebuf_bu = (uint*)alloc((size_t)NB * CAP * sizeof(uint));
    ushort* csr_td = (ushort*)alloc((size_t)NB * CAP * sizeof(ushort));
    ushort* csr_bu = (ushort*)alloc((size_t)NB * CAP * sizeof(ushort));
    int* off_td = (int*)alloc((size_t)N_NODES * sizeof(int));
    int* off_bu = (int*)alloc((size_t)N_NODES * sizeof(int));
    ushort* deg_td = (ushort*)alloc((size_t)N_NODES * sizeof(ushort));
    ushort* deg_bu = (ushort*)alloc((size_t)N_NODES * sizeof(ushort));
    float* dinv_td = (float*)alloc((size_t)N_PAD * sizeof(float));
    float* dinv_bu = (float*)alloc((size_t)N_PAD * sizeof(float));
    ushort* Bt1 = (ushort*)alloc((size_t)256 * 256 * sizeof(ushort));
    ushort* Wt2 = (ushort*)alloc((size_t)128 * 256 * sizeof(ushort));
    ushort* linb = (ushort*)alloc((size_t)N_PAD * F_CAT * sizeof(ushort));
    ushort* h1s  = (ushort*)alloc((size_t)N_PAD * F_CAT * sizeof(ushort));

    hipMemsetAsync(zreg, 0, zsz, stream);

    // ---- degrees + dinv (must precede the fused GEMM's epilogue) ----
    deg_kernel<<<(N_EDGES + 255) / 256, 256, 0, stream>>>(ei, cnt_td, cnt_bu);
    dinv_kernel<<<(N_PAD + 255) / 256, 256, 0, stream>>>(cnt_td, cnt_bu, dinv_td, dinv_bu);

    // ---- weights prep ----
    prep_w_kernel<<<256, 256, 0, stream>>>(td_W1, bu_W1, td_W2, bu_W2, Bt1, Wt2);

    // ---- fused: layer-1 GEMM (f32 A, in-flight cvt) + edge bucket-scatter ----
    gemm_scatter_kernel<<<GEMM_BLOCKS + N_EDGES / EPB, 256, 0, stream>>>(
        x, Bt1, linb, dinv_td, dinv_bu, ei, gcur, ebuf_td, ebuf_bu);

    // ---- CSR build ----
    csr_build_kernel<<<dim3(NB, 2), 256, 0, stream>>>(ebuf_td, ebuf_bu, gcur,
        off_td, off_bu, deg_td, deg_bu, csr_td, csr_bu);

    // ---- layer-1 aggregation ----
    agg1_kernel<<<N_NODES / 16, 256, 0, stream>>>(linb, h1s,
        csr_td, off_td, deg_td, dinv_td, csr_bu, off_bu, deg_bu, dinv_bu, td_b1, bu_b1);

    // ---- layer-2 aggregation + pool (W2 deferred to head) ----
    agg2_pool_kernel<<<N_NODES / 16, 256, 0, stream>>>(h1s, pooled_pre, batch,
        csr_td, off_td, deg_td, dinv_td, csr_bu, off_bu, deg_bu, dinv_bu);

    // ---- head: W2 matvec + cnt*b2 + MLP ----
    head_kernel<<<N_GRAPHS, 256, 0, stream>>>(pooled_pre, batch, Wt2,
        td_b2, bu_b2, pw1, pb1, pw2, pb2, out);
}

// Round 11
// 345.310 us; speedup vs baseline: 2.6822x; 1.1881x over previous
//
#include <hip/hip_runtime.h>

#define N_NODES 50000
#define N_PAD   50048   // 391*128, GEMM epilogue needs no row guards
#define N_EDGES 800000
#define N_GRAPHS 512
#define F_IN 256
#define F_H 128
#define F_CAT 256

// bucketed CSR build
#define BSHIFT 9
#define NB 98           // ceil(50000/512) buckets
#define CAP 10240       // edge capacity per bucket (mean 8163, 23 sigma slack)
#define EPB 3125        // edges per scatter block (256 blocks)

typedef __attribute__((ext_vector_type(8))) short short8;
typedef __attribute__((ext_vector_type(4))) float f32x4;
typedef unsigned int uint;
typedef unsigned short ushort;

static __device__ __forceinline__ ushort f2bf(float f) {
    uint u = __float_as_uint(f);
    u += 0x7FFF + ((u >> 16) & 1);  // RNE
    return (ushort)(u >> 16);
}
static __device__ __forceinline__ float bflo(uint v) { return __uint_as_float(v << 16); }
static __device__ __forceinline__ float bfhi(uint v) { return __uint_as_float(v & 0xFFFF0000u); }
static __device__ __forceinline__ float bfu(ushort v) { return __uint_as_float((uint)v << 16); }

// async global->LDS, 16B per lane; lds base must be wave-uniform
#define GLL(g, l) __builtin_amdgcn_global_load_lds( \
    (const __attribute__((address_space(1))) unsigned int*)(g), \
    (__attribute__((address_space(3))) unsigned int*)(l), 16, 0, 0)

// ---------------------------------------------------------------------------
// S1: bucket-scatter edges. gcur is RELATIVE (zero-initialized by memset).
__global__ __launch_bounds__(256) void csr_scatter_kernel(
        const int* __restrict__ ei, int* __restrict__ gcur,
        uint* __restrict__ ebuf_td, uint* __restrict__ ebuf_bu) {
    __shared__ int lcnt[256];   // [dir*128 + bucket]
    __shared__ int lbase[256];
    int tid = threadIdx.x;
    lcnt[tid] = 0;
    __syncthreads();
    int e0 = blockIdx.x * EPB;
    for (int k = tid; k < EPB; k += 256) {
        int i = e0 + k;
        int s = ei[i], d = ei[N_EDGES + i];
        atomicAdd(&lcnt[d >> BSHIFT], 1);
        atomicAdd(&lcnt[128 + (s >> BSHIFT)], 1);
    }
    __syncthreads();
    if (tid < 2 * NB) {
        int dir = tid / NB, b = tid % NB;
        int c = lcnt[dir * 128 + b];
        lbase[dir * 128 + b] = c ? atomicAdd(&gcur[dir * NB + b], c) : 0;
    }
    __syncthreads();
    lcnt[tid] = 0;
    __syncthreads();
    for (int k = tid; k < EPB; k += 256) {
        int i = e0 + k;
        int s = ei[i], d = ei[N_EDGES + i];
        int bd = d >> BSHIFT, bs = s >> BSHIFT;
        int p = atomicAdd(&lcnt[bd], 1) + lbase[bd];
        ebuf_td[(size_t)bd * CAP + p] = (uint)s | ((uint)(d & 511) << 16);
        int q = atomicAdd(&lcnt[128 + bs], 1) + lbase[128 + bs];
        ebuf_bu[(size_t)bs * CAP + q] = (uint)d | ((uint)(s & 511) << 16);
    }
}

// ---------------------------------------------------------------------------
// S2: per-(bucket,dir) CSR build; also emits deg (u16) + dinv (free here,
// the node histogram already exists). Bucket-local scatter window.
__global__ __launch_bounds__(256) void csr_build_kernel(
        const uint* __restrict__ ebuf_td, const uint* __restrict__ ebuf_bu,
        const int* __restrict__ gcur,
        int* off_td, int* off_bu, ushort* deg_td, ushort* deg_bu,
        float* dinv_td, float* dinv_bu, ushort* csr_td, ushort* csr_bu) {
    int b = blockIdx.x, dir = blockIdx.y;
    const uint* ebuf = dir ? ebuf_bu : ebuf_td;
    int* off     = dir ? off_bu : off_td;
    ushort* deg  = dir ? deg_bu : deg_td;
    float* dinv  = dir ? dinv_bu : dinv_td;
    ushort* csr  = dir ? csr_bu : csr_td;
    __shared__ int cntL[512], offL[512], sm[256];
    int tid = threadIdx.x;
    cntL[tid] = 0; cntL[tid + 256] = 0;
    __syncthreads();
    int rbeg = b * CAP;
    int rend = rbeg + gcur[dir * NB + b];
    for (int k = rbeg + tid; k < rend; k += 256)
        atomicAdd(&cntL[ebuf[k] >> 16], 1);
    __syncthreads();
    int a0 = cntL[tid * 2], a1 = cntL[tid * 2 + 1];
    int ps = a0 + a1;
    sm[tid] = ps;
    __syncthreads();
    for (int o = 1; o < 256; o <<= 1) {
        int u = (tid >= o) ? sm[tid - o] : 0;
        __syncthreads();
        sm[tid] += u;
        __syncthreads();
    }
    int excl = sm[tid] - ps;
    offL[tid * 2] = excl;
    offL[tid * 2 + 1] = excl + a0;
    __syncthreads();
    int nbase = b << BSHIFT;
#pragma unroll
    for (int j = 0; j < 2; j++) {
        int nloc = tid + j * 256;
        int n = nbase + nloc;
        if (n < N_NODES) {
            off[n] = rbeg + offL[nloc];
            int c = cntL[nloc];
            deg[n] = (ushort)c;
            dinv[n] = rsqrtf((float)c + 1.0f);
        }
    }
    // pad rows (only needed once; bucket NB-1, dir both cover [50000, N_PAD))
    if (b == NB - 1) {
        int n = N_NODES + tid;
        if (n < N_PAD) dinv[n] = 1.0f;
    }
    cntL[tid] = offL[tid];
    cntL[tid + 256] = offL[tid + 256];
    __syncthreads();
    for (int k = rbeg + tid; k < rend; k += 256) {
        uint e = ebuf[k];
        int slot = atomicAdd(&cntL[e >> 16], 1);
        csr[rbeg + slot] = (ushort)(e & 0xFFFF);
    }
}

// ---------------------------------------------------------------------------
// Bt1[n][k]; Wt2[k][c] with c in concat([bu, td]) order.
__global__ void prep_w_kernel(const float* __restrict__ td_W1, const float* __restrict__ bu_W1,
                              const float* __restrict__ td_W2, const float* __restrict__ bu_W2,
                              ushort* __restrict__ Bt1, ushort* __restrict__ Wt2) {
    int n = blockIdx.x;   // 0..255
    int k = threadIdx.x;  // 0..255
    float w1 = (n < F_H) ? td_W1[(size_t)k * F_H + n] : bu_W1[(size_t)k * F_H + (n - F_H)];
    Bt1[(size_t)n * 256 + k] = f2bf(w1);
    if (k < 128) {
        float w2 = (n < F_H) ? bu_W2[(size_t)k * F_H + n]
                             : td_W2[(size_t)k * F_H + (n - F_H)];
        Wt2[(size_t)k * 256 + n] = f2bf(w2);
    }
}

// ---------------------------------------------------------------------------
// MFMA GEMM (layer 1): A = x f32 (in-register bf16 convert), B via GLL,
// C = linb bf16 row-scaled by branch dinv. 128x128 tile, BK=32, 4 waves.
__global__ __launch_bounds__(256) void gemm_mfma(
        const float* __restrict__ x, const ushort* __restrict__ Bt,
        ushort* __restrict__ C,
        const float* __restrict__ dinv_td, const float* __restrict__ dinv_bu) {
    __shared__ __align__(16) ushort As[128 * 32];
    __shared__ __align__(16) ushort Bs[128 * 32];
    int tid = threadIdx.x;
    int wave = tid >> 6, lane = tid & 63, quad = lane >> 4, l16 = lane & 15;
    size_t bm = (size_t)blockIdx.x * 128;
    size_t bn = (size_t)blockIdx.y * 128;
    const float* dsel = blockIdx.y ? dinv_bu : dinv_td;

    f32x4 acc[2][8];
    const f32x4 z4 = {0.f, 0.f, 0.f, 0.f};
#pragma unroll
    for (int i = 0; i < 2; i++)
#pragma unroll
        for (int j = 0; j < 8; j++) acc[i][j] = z4;

    // A staging (f32 -> bf16 in regs): thread covers rows ar+32j, kcols akq..+3
    int ar = tid >> 3;          // 0..31
    int akq = (tid & 7) * 4;    // 0..28
    // B staging via GLL: 512 x 16B chunks, 2 per thread
    int cb0 = wave * 64;
    int cb1 = 256 + wave * 64;
    int c0 = cb0 + lane, c1 = cb1 + lane;
    int r0 = c0 >> 2, s0 = (c0 & 3) * 8;
    int r1 = c1 >> 2, s1 = (c1 & 3) * 8;
    const ushort* b0p = Bt + (bn + r0) * 256 + s0;
    const ushort* b1p = Bt + (bn + r1) * 256 + s1;
    ushort* lB0 = Bs + cb0 * 8;
    ushort* lB1 = Bs + cb1 * 8;

    for (int kb = 0; kb < 8; kb++) {
        int k0 = kb * 32;
        float4 av[4];
#pragma unroll
        for (int j = 0; j < 4; j++) {
            size_t grow = bm + ar + j * 32;
            if (grow < N_NODES)
                av[j] = *(const float4*)(x + grow * F_IN + k0 + akq);
            else
                av[j] = make_float4(0.f, 0.f, 0.f, 0.f);
        }
        __syncthreads();  // previous iter's fragment reads done
        GLL(b0p + k0, lB0);
        GLL(b1p + k0, lB1);
#pragma unroll
        for (int j = 0; j < 4; j++) {
            ushort4 u;
            u.x = f2bf(av[j].x); u.y = f2bf(av[j].y);
            u.z = f2bf(av[j].z); u.w = f2bf(av[j].w);
            *(ushort4*)(As + (ar + j * 32) * 32 + akq) = u;
        }
        __syncthreads();  // drains vmcnt + lgkm, tiles ready
        short8 af0 = *(const short8*)(As + (wave * 32 + l16) * 32 + quad * 8);
        short8 af1 = *(const short8*)(As + (wave * 32 + 16 + l16) * 32 + quad * 8);
#pragma unroll
        for (int ct = 0; ct < 8; ct++) {
            short8 bfr = *(const short8*)(Bs + (ct * 16 + l16) * 32 + quad * 8);
            acc[0][ct] = __builtin_amdgcn_mfma_f32_16x16x32_bf16(af0, bfr, acc[0][ct], 0, 0, 0);
            acc[1][ct] = __builtin_amdgcn_mfma_f32_16x16x32_bf16(af1, bfr, acc[1][ct], 0, 0, 0);
        }
    }
#pragma unroll
    for (int rt = 0; rt < 2; rt++) {
#pragma unroll
        for (int r = 0; r < 4; r++) {
            size_t row = bm + wave * 32 + rt * 16 + quad * 4 + r;
            float dv = dsel[row];
#pragma unroll
            for (int ct = 0; ct < 8; ct++) {
                C[row * 256 + bn + ct * 16 + l16] = f2bf(acc[rt][ct][r] * dv);
            }
        }
    }
}

// ---------------------------------------------------------------------------
// Wave-gather: lane = half*32 + l32; l32 covers 4 cols (uint2), half selects
// one of 2 concurrent edge rows. Unroll-8 -> 16 edges in flight per wave.
static __device__ __forceinline__ void gather_node(
        const ushort* __restrict__ base, const ushort* __restrict__ csr,
        int kb, int ke, int half, float a[4]) {
    float p[4] = {0.f, 0.f, 0.f, 0.f};
    float q[4] = {0.f, 0.f, 0.f, 0.f};
    float r[4] = {0.f, 0.f, 0.f, 0.f};
    int k = kb;
    for (; k + 16 <= ke; k += 16) {
        int i0 = csr[k + half],      i1 = csr[k + 2 + half];
        int i2 = csr[k + 4 + half],  i3 = csr[k + 6 + half];
        int i4 = csr[k + 8 + half],  i5 = csr[k + 10 + half];
        int i6 = csr[k + 12 + half], i7 = csr[k + 14 + half];
        uint2 v0 = *(const uint2*)(base + (size_t)i0 * F_CAT);
        uint2 v1 = *(const uint2*)(base + (size_t)i1 * F_CAT);
        uint2 v2 = *(const uint2*)(base + (size_t)i2 * F_CAT);
        uint2 v3 = *(const uint2*)(base + (size_t)i3 * F_CAT);
        uint2 v4 = *(const uint2*)(base + (size_t)i4 * F_CAT);
        uint2 v5 = *(const uint2*)(base + (size_t)i5 * F_CAT);
        uint2 v6 = *(const uint2*)(base + (size_t)i6 * F_CAT);
        uint2 v7 = *(const uint2*)(base + (size_t)i7 * F_CAT);
        a[0] += bflo(v0.x); a[1] += bfhi(v0.x); a[2] += bflo(v0.y); a[3] += bfhi(v0.y);
        p[0] += bflo(v1.x); p[1] += bfhi(v1.x); p[2] += bflo(v1.y); p[3] += bfhi(v1.y);
        q[0] += bflo(v2.x); q[1] += bfhi(v2.x); q[2] += bflo(v2.y); q[3] += bfhi(v2.y);
        r[0] += bflo(v3.x); r[1] += bfhi(v3.x); r[2] += bflo(v3.y); r[3] += bfhi(v3.y);
        a[0] += bflo(v4.x); a[1] += bfhi(v4.x); a[2] += bflo(v4.y); a[3] += bfhi(v4.y);
        p[0] += bflo(v5.x); p[1] += bfhi(v5.x); p[2] += bflo(v5.y); p[3] += bfhi(v5.y);
        q[0] += bflo(v6.x); q[1] += bfhi(v6.x); q[2] += bflo(v6.y); q[3] += bfhi(v6.y);
        r[0] += bflo(v7.x); r[1] += bfhi(v7.x); r[2] += bflo(v7.y); r[3] += bfhi(v7.y);
    }
    for (; k + 8 <= ke; k += 8) {
        int i0 = csr[k + half],     i1 = csr[k + 2 + half];
        int i2 = csr[k + 4 + half], i3 = csr[k + 6 + half];
        uint2 v0 = *(const uint2*)(base + (size_t)i0 * F_CAT);
        uint2 v1 = *(const uint2*)(base + (size_t)i1 * F_CAT);
        uint2 v2 = *(const uint2*)(base + (size_t)i2 * F_CAT);
        uint2 v3 = *(const uint2*)(base + (size_t)i3 * F_CAT);
        a[0] += bflo(v0.x); a[1] += bfhi(v0.x); a[2] += bflo(v0.y); a[3] += bfhi(v0.y);
        p[0] += bflo(v1.x); p[1] += bfhi(v1.x); p[2] += bflo(v1.y); p[3] += bfhi(v1.y);
        q[0] += bflo(v2.x); q[1] += bfhi(v2.x); q[2] += bflo(v2.y); q[3] += bfhi(v2.y);
        r[0] += bflo(v3.x); r[1] += bfhi(v3.x); r[2] += bflo(v3.y); r[3] += bfhi(v3.y);
    }
    for (; k < ke; k += 2) {
        int kk = k + half;
        if (kk < ke) {
            uint2 v = *(const uint2*)(base + (size_t)csr[kk] * F_CAT);
            a[0] += bflo(v.x); a[1] += bfhi(v.x); a[2] += bflo(v.y); a[3] += bfhi(v.y);
        }
    }
#pragma unroll
    for (int j = 0; j < 4; j++) a[j] += (p[j] + q[j]) + r[j];
}

// ---------------------------------------------------------------------------
// Layer-1 aggregation. Wave handles 8 consecutive nodes of one branch.
// h1s[n] = relu(dn*(self+neigh) + b1) * dn   (dinv pre-folded for layer 2)
__global__ __launch_bounds__(256) void agg1_kernel(
        const ushort* __restrict__ linS, ushort* __restrict__ h1s,
        const ushort* __restrict__ csr_td, const int* __restrict__ off_td,
        const ushort* __restrict__ deg_td, const float* __restrict__ dinv_td,
        const ushort* __restrict__ csr_bu, const int* __restrict__ off_bu,
        const ushort* __restrict__ deg_bu, const float* __restrict__ dinv_bu,
        const float* __restrict__ b_td, const float* __restrict__ b_bu) {
    int wave = threadIdx.x >> 6, lane = threadIdx.x & 63;
    int n0 = (blockIdx.x * 2 + (wave >> 1)) * 8;
    int br = wave & 1;
    const ushort* csr = br ? csr_bu : csr_td;
    const int* off    = br ? off_bu : off_td;
    const ushort* deg = br ? deg_bu : deg_td;
    const float* dinv = br ? dinv_bu : dinv_td;
    const float* bias = br ? b_bu : b_td;
    int half = lane >> 5, l32 = lane & 31;
    int col = br * F_H + l32 * 4;
    const ushort* base = linS + col;
    int bcol = l32 * 4;
    float bs0 = bias[bcol], bs1 = bias[bcol + 1];
    float bs2 = bias[bcol + 2], bs3 = bias[bcol + 3];

#pragma unroll
    for (int j = 0; j < 8; j++) {
        int n = n0 + j;
        float a[4] = {0.f, 0.f, 0.f, 0.f};
        int kb = off[n];
        gather_node(base, csr, kb, kb + deg[n], half, a);
#pragma unroll
        for (int t = 0; t < 4; t++) a[t] += __shfl_xor(a[t], 32);
        uint2 vs = *(const uint2*)(base + (size_t)n * F_CAT);  // self
        a[0] += bflo(vs.x); a[1] += bfhi(vs.x); a[2] += bflo(vs.y); a[3] += bfhi(vs.y);
        float dn = dinv[n];
        float o0 = fmaxf(a[0] * dn + bs0, 0.f) * dn;
        float o1 = fmaxf(a[1] * dn + bs1, 0.f) * dn;
        float o2 = fmaxf(a[2] * dn + bs2, 0.f) * dn;
        float o3 = fmaxf(a[3] * dn + bs3, 0.f) * dn;
        if (half == 0) {
            uint2 pk;
            pk.x = (uint)f2bf(o0) | ((uint)f2bf(o1) << 16);
            pk.y = (uint)f2bf(o2) | ((uint)f2bf(o3) << 16);
            *(uint2*)(h1s + (size_t)n * F_CAT + col) = pk;
        }
    }
}

// ---------------------------------------------------------------------------
// Layer-2 aggregation fused with pooling (pool-before-W2 algebra):
// pooled_pre[g, col] += dn*(self + neigh) over nodes of graph g.
__global__ __launch_bounds__(256) void agg2_pool_kernel(
        const ushort* __restrict__ h1s, float* __restrict__ pooled_pre,
        const int* __restrict__ batch,
        const ushort* __restrict__ csr_td, const int* __restrict__ off_td,
        const ushort* __restrict__ deg_td, const float* __restrict__ dinv_td,
        const ushort* __restrict__ csr_bu, const int* __restrict__ off_bu,
        const ushort* __restrict__ deg_bu, const float* __restrict__ dinv_bu) {
    int wave = threadIdx.x >> 6, lane = threadIdx.x & 63;
    int n0 = (blockIdx.x * 2 + (wave >> 1)) * 8;
    int br = wave & 1;
    const ushort* csr = br ? csr_bu : csr_td;
    const int* off    = br ? off_bu : off_td;
    const ushort* deg = br ? deg_bu : deg_td;
    const float* dinv = br ? dinv_bu : dinv_td;
    int half = lane >> 5, l32 = lane & 31;
    int col = br * F_H + l32 * 4;
    const ushort* base = h1s + col;

    float acc0 = 0.f, acc1 = 0.f, acc2 = 0.f, acc3 = 0.f;
    int gcur = batch[n0];
#pragma unroll
    for (int j = 0; j < 8; j++) {
        int n = n0 + j;
        int g = batch[n];
        if (g != gcur) {  // wave-uniform
            if (half == 0) {
                float* pp = &pooled_pre[(size_t)gcur * F_CAT + col];
                unsafeAtomicAdd(pp,     acc0);
                unsafeAtomicAdd(pp + 1, acc1);
                unsafeAtomicAdd(pp + 2, acc2);
                unsafeAtomicAdd(pp + 3, acc3);
            }
            acc0 = acc1 = acc2 = acc3 = 0.f;
            gcur = g;
        }
        float a[4] = {0.f, 0.f, 0.f, 0.f};
        int kb = off[n];
        gather_node(base, csr, kb, kb + deg[n], half, a);
#pragma unroll
        for (int t = 0; t < 4; t++) a[t] += __shfl_xor(a[t], 32);
        uint2 vs = *(const uint2*)(base + (size_t)n * F_CAT);
        a[0] += bflo(vs.x); a[1] += bfhi(vs.x); a[2] += bflo(vs.y); a[3] += bfhi(vs.y);
        float dn = dinv[n];
        acc0 += a[0] * dn;
        acc1 += a[1] * dn;
        acc2 += a[2] * dn;
        acc3 += a[3] * dn;
    }
    if (half == 0) {
        float* pp = &pooled_pre[(size_t)gcur * F_CAT + col];
        unsafeAtomicAdd(pp,     acc0);
        unsafeAtomicAdd(pp + 1, acc1);
        unsafeAtomicAdd(pp + 2, acc2);
        unsafeAtomicAdd(pp + 3, acc3);
    }
}

// ---------------------------------------------------------------------------
// Head: z = pooled_pre @ W2 (per branch) + cnt*b2 in concat([bu,td]) order,
// then MLP relu(z@pw1+pb1)@pw2+pb2. One block per graph.
__global__ __launch_bounds__(256) void head_kernel(
        const float* __restrict__ pooled_pre, const int* __restrict__ batch,
        const ushort* __restrict__ Wt2,
        const float* __restrict__ td_b2, const float* __restrict__ bu_b2,
        const float* __restrict__ pw1, const float* __restrict__ pb1,
        const float* __restrict__ pw2, const float* __restrict__ pb2,
        float* __restrict__ out) {
    int g = blockIdx.x;
    int tid = threadIdx.x;
    __shared__ float row[256], z[256], hid[256];
    row[tid] = pooled_pre[(size_t)g * 256 + tid];
    int lo = 0, hi = N_NODES;
    while (lo < hi) { int m = (lo + hi) >> 1; if (batch[m] < g) lo = m + 1; else hi = m; }
    int start = lo;
    lo = start; hi = N_NODES;
    while (lo < hi) { int m = (lo + hi) >> 1; if (batch[m] < g + 1) lo = m + 1; else hi = m; }
    float cnt = (float)(lo - start);
    __syncthreads();
    const float* rsel = (tid < 128) ? (row + F_H) : row;
    float b2 = (tid < 128) ? bu_b2[tid] : td_b2[tid - F_H];
    float acc = cnt * b2;
    for (int k = 0; k < F_H; k++) acc += rsel[k] * bfu(Wt2[(size_t)k * 256 + tid]);
    z[tid] = acc;
    __syncthreads();
    float h = pb1[tid];
    for (int k = 0; k < 256; k++) h += z[k] * pw1[(size_t)k * 256 + tid];
    hid[tid] = fmaxf(h, 0.f);
    __syncthreads();
    if (tid < 128) {
        float o = pb2[tid];
        for (int k = 0; k < 256; k++) o += hid[k] * pw2[(size_t)k * 128 + tid];
        out[(size_t)g * 128 + tid] = o;
    }
}

// ---------------------------------------------------------------------------
extern "C" void kernel_launch(void* const* d_in, const int* in_sizes, int n_in,
                              void* d_out, int out_size, void* d_ws, size_t ws_size,
                              hipStream_t stream) {
    const float* x     = (const float*)d_in[0];
    const int*   ei    = (const int*)d_in[1];
    const int*   batch = (const int*)d_in[2];
    const float* td_W1 = (const float*)d_in[4];
    const float* td_b1 = (const float*)d_in[5];
    const float* td_W2 = (const float*)d_in[6];
    const float* td_b2 = (const float*)d_in[7];
    const float* bu_W1 = (const float*)d_in[8];
    const float* bu_b1 = (const float*)d_in[9];
    const float* bu_W2 = (const float*)d_in[10];
    const float* bu_b2 = (const float*)d_in[11];
    const float* pw1   = (const float*)d_in[12];
    const float* pb1   = (const float*)d_in[13];
    const float* pw2   = (const float*)d_in[14];
    const float* pb2   = (const float*)d_in[15];
    float* out = (float*)d_out;

    // ---- workspace carve ----
    char* p = (char*)d_ws;
    auto alloc = [&](size_t bytes) { void* r = (void*)p; p += (bytes + 255) & ~(size_t)255; return r; };
    // single memset region: gcur (1 KB) + pooled_pre (512 KB)
    char* zreg = (char*)alloc(1024 + (size_t)N_GRAPHS * F_CAT * sizeof(float));
    int* gcur = (int*)zreg;
    float* pooled_pre = (float*)(zreg + 1024);
    uint* ebuf_td = (uint*)alloc((size_t)NB * CAP * sizeof(uint));
    uint* ebuf_bu = (uint*)alloc((size_t)NB * CAP * sizeof(uint));
    ushort* csr_td = (ushort*)alloc((size_t)NB * CAP * sizeof(ushort));
    ushort* csr_bu = (ushort*)alloc((size_t)NB * CAP * sizeof(ushort));
    int* off_td = (int*)alloc((size_t)N_NODES * sizeof(int));
    int* off_bu = (int*)alloc((size_t)N_NODES * sizeof(int));
    ushort* deg_td = (ushort*)alloc((size_t)N_NODES * sizeof(ushort));
    ushort* deg_bu = (ushort*)alloc((size_t)N_NODES * sizeof(ushort));
    float* dinv_td = (float*)alloc((size_t)N_PAD * sizeof(float));
    float* dinv_bu = (float*)alloc((size_t)N_PAD * sizeof(float));
    ushort* Bt1 = (ushort*)alloc((size_t)256 * 256 * sizeof(ushort));
    ushort* Wt2 = (ushort*)alloc((size_t)128 * 256 * sizeof(ushort));
    ushort* linb = (ushort*)alloc((size_t)N_PAD * F_CAT * sizeof(ushort));
    ushort* h1s  = (ushort*)alloc((size_t)N_PAD * F_CAT * sizeof(ushort));

    hipMemsetAsync(zreg, 0, 1024 + (size_t)N_GRAPHS * F_CAT * sizeof(float), stream);

    // ---- weights prep ----
    prep_w_kernel<<<256, 256, 0, stream>>>(td_W1, bu_W1, td_W2, bu_W2, Bt1, Wt2);

    // ---- graph structure (bucketed counting sort; csr_build emits dinv) ----
    csr_scatter_kernel<<<N_EDGES / EPB, 256, 0, stream>>>(ei, gcur, ebuf_td, ebuf_bu);
    csr_build_kernel<<<dim3(NB, 2), 256, 0, stream>>>(ebuf_td, ebuf_bu, gcur,
        off_td, off_bu, deg_td, deg_bu, dinv_td, dinv_bu, csr_td, csr_bu);

    // ---- layer 1: GEMM (f32 A, in-register cvt; dinv ready) ----
    dim3 gg(N_PAD / 128, 2);
    gemm_mfma<<<gg, 256, 0, stream>>>(x, Bt1, linb, dinv_td, dinv_bu);
    agg1_kernel<<<N_NODES / 16, 256, 0, stream>>>(linb, h1s,
        csr_td, off_td, deg_td, dinv_td, csr_bu, off_bu, deg_bu, dinv_bu, td_b1, bu_b1);

    // ---- layer 2: aggregation + pool (W2 deferred to head) ----
    agg2_pool_kernel<<<N_NODES / 16, 256, 0, stream>>>(h1s, pooled_pre, batch,
        csr_td, off_td, deg_td, dinv_td, csr_bu, off_bu, deg_bu, dinv_bu);

    // ---- head: W2 matvec + cnt*b2 + MLP ----
    head_kernel<<<N_GRAPHS, 256, 0, stream>>>(pooled_pre, batch, Wt2,
        td_b2, bu_b2, pw1, pb1, pw2, pb2, out);
}